// Round 1
// baseline (1322.830 us; speedup 1.0000x reference)
//
#include <hip/hip_runtime.h>
#include <math.h>

#define BB 512
#define NN 128
#define CAND_CAP (512*384)
#define LIMIT 2048

// ---------------- mask decode (int32 / byte / float32 robustness) -------------
__device__ inline bool read_mask(const void* p, int i, int mode){
  if (mode == 0) return ((const int*)p)[i] != 0;
  if (mode == 1) return ((const unsigned char*)p)[i] != 0;
  return ((const float*)p)[i] != 0.0f;
}

__global__ void kmode_kernel(const void* m, int* hdr){
  if (threadIdx.x == 0 && blockIdx.x == 0){
    const unsigned* u = (const unsigned*)m;
    bool a01 = true, af = true;
    for (int i = 0; i < 64; i++){
      unsigned v = u[i];
      a01 = a01 && (v == 0u || v == 1u);
      af  = af  && (v == 0u || v == 0x3F800000u);
    }
    hdr[3] = a01 ? 0 : (af ? 2 : 1);
  }
}

// ---------------- K1: exp, mutual top-3, candidates, per-batch H/sc/rc --------
__global__ __launch_bounds__(128) void k1_kernel(
    const float* __restrict__ score, const float* __restrict__ refp,
    const float* __restrict__ srcp, const void* __restrict__ rmaskp,
    const void* __restrict__ smaskp, int* hdr, float* cand_vals, int* cand_idx,
    float* Hsr, int* pcount)
{
  __shared__ float tile[NN*NN];      // 64 KB exp-score tile (gfx950: 160KB LDS ok)
  __shared__ float t3col[NN];
  __shared__ float smaskv[NN];
  __shared__ float srcsh[NN*3];
  __shared__ float red[2][17];
  const int b = blockIdx.x, t = threadIdx.x;
  const int mode = hdr[3];

  // coalesced load + exp
  const float4* s4 = (const float4*)(score + (size_t)b*NN*NN);
  float4* t4 = (float4*)tile;
  for (int j = t; j < NN*NN/4; j += NN){
    float4 v = s4[j];
    v.x = expf(v.x); v.y = expf(v.y); v.z = expf(v.z); v.w = expf(v.w);
    t4[j] = v;
  }
  smaskv[t] = read_mask(smaskp, b*NN + t, mode) ? 1.f : 0.f;
  const float rm = read_mask(rmaskp, b*NN + t, mode) ? 1.f : 0.f;
  const float rx = refp[(b*NN+t)*3+0], ry = refp[(b*NN+t)*3+1], rz = refp[(b*NN+t)*3+2];
  srcsh[t*3+0] = srcp[(b*NN+t)*3+0];
  srcsh[t*3+1] = srcp[(b*NN+t)*3+1];
  srcsh[t*3+2] = srcp[(b*NN+t)*3+2];
  __syncthreads();

  // column top-3 (thread t owns column t): 2-way bank alias = free
  float c1=-1e30f, c2=-1e30f, c3=-1e30f;
  for (int n = 0; n < NN; n++){
    float v = tile[n*NN + t];
    if (v > c1){ c3=c2; c2=c1; c1=v; } else if (v > c2){ c3=c2; c2=v; } else if (v > c3){ c3=v; }
  }
  t3col[t] = c3;
  // row top-3 (thread t owns row t), rotated to avoid 64-way conflicts
  float r1=-1e30f, r2=-1e30f, r3v=-1e30f;
  for (int i = 0; i < NN; i++){
    int m = (t + i) & (NN - 1);
    float v = tile[t*NN + m];
    if (v > r1){ r3v=r2; r2=r1; r1=v; } else if (v > r2){ r3v=r2; r2=v; } else if (v > r3v){ r3v=v; }
  }
  __syncthreads();

  // masked pass: keep mutual-top-3 & >CONF & masks; emit candidates; row stats
  float wr = 0.f, p0 = 0.f, p1 = 0.f, p2 = 0.f, cntf = 0.f;
  for (int i = 0; i < NN; i++){
    int m = (t + i) & (NN - 1);
    float v = tile[t*NN + m];
    bool keep = (rm > 0.f) && (smaskv[m] > 0.f) && (v > 0.05f) && (v >= r3v) && (v >= t3col[m]);
    if (keep){
      cntf += 1.f; wr += v;
      p0 += v*srcsh[m*3+0]; p1 += v*srcsh[m*3+1]; p2 += v*srcsh[m*3+2];
      int pos = atomicAdd(&hdr[0], 1);
      if (pos < CAND_CAP){ cand_vals[pos] = v; cand_idx[pos] = (b<<14)|(t<<7)|m; }
    } else {
      tile[t*NN + m] = 0.f;
    }
  }
  __syncthreads();

  // column sums of masked values
  float wc = 0.f;
  for (int n = 0; n < NN; n++) wc += tile[n*NN + t];
  float sx = srcsh[t*3+0], sy = srcsh[t*3+1], sz = srcsh[t*3+2];

  float q[17];
  q[0]=cntf; q[1]=wr;
  q[2]=wr*rx; q[3]=wr*ry; q[4]=wr*rz;       // rc numerator
  q[5]=wc*sx; q[6]=wc*sy; q[7]=wc*sz;       // sc numerator
  q[8]=p0*rx;  q[9]=p0*ry;  q[10]=p0*rz;    // M^[c][d] = sum p_c * ref_d
  q[11]=p1*rx; q[12]=p1*ry; q[13]=p1*rz;
  q[14]=p2*rx; q[15]=p2*ry; q[16]=p2*rz;
  int lane = t & 63, wv = t >> 6;
  for (int k = 0; k < 17; k++){
    float v = q[k];
    for (int off = 32; off > 0; off >>= 1) v += __shfl_down(v, off);
    if (lane == 0) red[wv][k] = v;
  }
  __syncthreads();
  if (t == 0){
    float tot[17];
    for (int k = 0; k < 17; k++) tot[k] = red[0][k] + red[1][k];
    float Wm = tot[1];
    float denom = Wm + 1e-5f;
    float s = Wm / denom;
    float rcv[3] = { tot[2]/denom, tot[3]/denom, tot[4]/denom };
    float scv[3] = { tot[5]/denom, tot[6]/denom, tot[7]/denom };
    float* o = &Hsr[b*15];
    for (int c = 0; c < 3; c++)
      for (int d = 0; d < 3; d++)
        o[c*3+d] = tot[8 + c*3 + d]/denom - (2.f - s)*scv[c]*rcv[d];
    o[9]=scv[0]; o[10]=scv[1]; o[11]=scv[2];
    o[12]=rcv[0]; o[13]=rcv[1]; o[14]=rcv[2];
    pcount[b] = (int)(tot[0] + 0.5f);
  }
}

// ---------------- Kabsch rotation from 3x3 covariance (double Jacobi) ---------
__device__ void kabsch_rot(const double H[3][3], double R[3][3]){
  double S[3][3];
  for (int i = 0; i < 3; i++)
    for (int j = 0; j < 3; j++){
      double a = 0.0;
      for (int k = 0; k < 3; k++) a += H[k][i]*H[k][j];
      S[i][j] = a;
    }
  double V[3][3] = {{1,0,0},{0,1,0},{0,0,1}};
  for (int sweep = 0; sweep < 30; sweep++){
    double off  = S[0][1]*S[0][1] + S[0][2]*S[0][2] + S[1][2]*S[1][2];
    double base = S[0][0]*S[0][0] + S[1][1]*S[1][1] + S[2][2]*S[2][2];
    if (off <= base*1e-28 + 1e-280) break;
    for (int p = 0; p < 2; p++)
      for (int q = p+1; q < 3; q++){
        double apq = S[p][q];
        if (fabs(apq) <= 1e-280) continue;
        double tau = (S[q][q] - S[p][p]) / (2.0*apq);
        double tt  = (tau >= 0.0 ? 1.0 : -1.0) / (fabs(tau) + sqrt(1.0 + tau*tau));
        double c = 1.0 / sqrt(1.0 + tt*tt), s = tt*c;
        for (int k = 0; k < 3; k++){ double a=S[k][p], b2=S[k][q]; S[k][p]=c*a-s*b2; S[k][q]=s*a+c*b2; }
        for (int k = 0; k < 3; k++){ double a=S[p][k], b2=S[q][k]; S[p][k]=c*a-s*b2; S[q][k]=s*a+c*b2; }
        for (int k = 0; k < 3; k++){ double a=V[k][p], b2=V[k][q]; V[k][p]=c*a-s*b2; V[k][q]=s*a+c*b2; }
      }
  }
  double lam[3] = { S[0][0], S[1][1], S[2][2] };
  int o0=0,o1=1,o2=2;
  if (lam[o0] < lam[o1]){ int x=o0;o0=o1;o1=x; }
  if (lam[o0] < lam[o2]){ int x=o0;o0=o2;o2=x; }
  if (lam[o1] < lam[o2]){ int x=o1;o1=o2;o2=x; }
  double v0[3]={V[0][o0],V[1][o0],V[2][o0]};
  double v1[3]={V[0][o1],V[1][o1],V[2][o1]};
  double v2[3]={V[0][o2],V[1][o2],V[2][o2]};
  double sig0 = sqrt(fmax(lam[o0], 0.0));
  if (!(sig0 > 1e-20)){
    for (int i = 0; i < 3; i++) for (int j = 0; j < 3; j++) R[i][j] = (i==j) ? 1.0 : 0.0;
    return;
  }
  double u0[3],u1[3],u2[3];
  for (int i = 0; i < 3; i++) u0[i] = H[i][0]*v0[0] + H[i][1]*v0[1] + H[i][2]*v0[2];
  double n0 = sqrt(u0[0]*u0[0]+u0[1]*u0[1]+u0[2]*u0[2]);
  for (int i = 0; i < 3; i++) u0[i] /= n0;
  for (int i = 0; i < 3; i++) u1[i] = H[i][0]*v1[0] + H[i][1]*v1[1] + H[i][2]*v1[2];
  double dp = u1[0]*u0[0]+u1[1]*u0[1]+u1[2]*u0[2];
  for (int i = 0; i < 3; i++) u1[i] -= dp*u0[i];
  double n1 = sqrt(u1[0]*u1[0]+u1[1]*u1[1]+u1[2]*u1[2]);
  if (n1 > sig0*1e-10){
    for (int i = 0; i < 3; i++) u1[i] /= n1;
  } else {
    int k = (fabs(u0[0])<=fabs(u0[1]) && fabs(u0[0])<=fabs(u0[2])) ? 0 : ((fabs(u0[1])<=fabs(u0[2])) ? 1 : 2);
    double e[3] = {0,0,0}; e[k] = 1.0;
    double d2 = e[0]*u0[0]+e[1]*u0[1]+e[2]*u0[2];
    for (int i = 0; i < 3; i++) u1[i] = e[i] - d2*u0[i];
    double nn = sqrt(u1[0]*u1[0]+u1[1]*u1[1]+u1[2]*u1[2]);
    for (int i = 0; i < 3; i++) u1[i] /= nn;
  }
  u2[0] = u0[1]*u1[2] - u0[2]*u1[1];
  u2[1] = u0[2]*u1[0] - u0[0]*u1[2];
  u2[2] = u0[0]*u1[1] - u0[1]*u1[0];
  double cx = v1[1]*v2[2] - v1[2]*v2[1];
  double cy = v1[2]*v2[0] - v1[0]*v2[2];
  double cz = v1[0]*v2[1] - v1[1]*v2[0];
  double detV = v0[0]*cx + v0[1]*cy + v0[2]*cz;  // det(U)=+1 by construction
  double dd = (detV >= 0.0) ? 1.0 : -1.0;
  for (int i = 0; i < 3; i++)
    for (int j = 0; j < 3; j++)
      R[i][j] = v0[i]*u0[j] + v1[i]*u1[j] + dd*v2[i]*u2[j];
}

// ---------------- K2: per-batch local transforms ------------------------------
__global__ void k2_kernel(const float* __restrict__ Hsr, float* __restrict__ localT){
  int b = blockIdx.x*blockDim.x + threadIdx.x;
  if (b >= BB) return;
  const float* o = &Hsr[b*15];
  double H[3][3];
  for (int c = 0; c < 3; c++) for (int d = 0; d < 3; d++) H[c][d] = (double)o[c*3+d];
  double sc[3] = { o[9], o[10], o[11] }, rc[3] = { o[12], o[13], o[14] };
  double R[3][3];
  kabsch_rot(H, R);
  float* T = &localT[b*12];
  for (int i = 0; i < 3; i++) for (int j = 0; j < 3; j++) T[i*3+j] = (float)R[i][j];
  for (int i = 0; i < 3; i++)
    T[9+i] = (float)(rc[i] - (R[i][0]*sc[0] + R[i][1]*sc[1] + R[i][2]*sc[2]));
}

// ---------------- K3: global top-2048 by 3-pass radix-select ------------------
__global__ __launch_bounds__(1024) void k3_kernel(
    const int* hdr, const float* __restrict__ cand_vals, const int* __restrict__ cand_idx,
    float* sel_vals, int* sel_idx)
{
  __shared__ int hist[2048];
  __shared__ int sh[8];
  __shared__ int eqidx[1024];
  const int t = threadIdx.x;
  int Nc = hdr[0]; if (Nc > CAND_CAP) Nc = CAND_CAP;
  if (Nc <= LIMIT){
    for (int i = t; i < LIMIT; i += 1024){
      if (i < Nc){ sel_vals[i] = cand_vals[i]; sel_idx[i] = cand_idx[i]; }
      else       { sel_vals[i] = 0.f; sel_idx[i] = 0; }
    }
    return;
  }
  // pass 1: bits 31..21
  for (int i = t; i < 2048; i += 1024) hist[i] = 0;
  __syncthreads();
  for (int i = t; i < Nc; i += 1024)
    atomicAdd(&hist[__float_as_uint(cand_vals[i]) >> 21], 1);
  __syncthreads();
  if (t == 0){
    int cum = 0, bin = 0;
    for (int j = 2047; j >= 0; j--){ if (cum + hist[j] >= LIMIT){ bin = j; break; } cum += hist[j]; }
    sh[0] = bin; sh[1] = LIMIT - cum;
  }
  __syncthreads();
  unsigned bin1 = (unsigned)sh[0]; int need1 = sh[1];
  // pass 2: bits 20..10 within bin1
  for (int i = t; i < 2048; i += 1024) hist[i] = 0;
  __syncthreads();
  for (int i = t; i < Nc; i += 1024){
    unsigned k = __float_as_uint(cand_vals[i]);
    if ((k >> 21) == bin1) atomicAdd(&hist[(k >> 10) & 0x7FF], 1);
  }
  __syncthreads();
  if (t == 0){
    int cum = 0, bin = 0;
    for (int j = 2047; j >= 0; j--){ if (cum + hist[j] >= need1){ bin = j; break; } cum += hist[j]; }
    sh[2] = bin; sh[3] = need1 - cum;
  }
  __syncthreads();
  unsigned bin2 = (unsigned)sh[2]; int need2 = sh[3];
  unsigned pref2 = (bin1 << 11) | bin2;
  // pass 3: bits 9..0 within (bin1,bin2)
  for (int i = t; i < 2048; i += 1024) hist[i] = 0;
  __syncthreads();
  for (int i = t; i < Nc; i += 1024){
    unsigned k = __float_as_uint(cand_vals[i]);
    if ((k >> 10) == pref2) atomicAdd(&hist[k & 0x3FF], 1);
  }
  __syncthreads();
  if (t == 0){
    int cum = 0, bin = 0;
    for (int j = 1023; j >= 0; j--){ if (cum + hist[j] >= need2){ bin = j; break; } cum += hist[j]; }
    sh[4] = bin; sh[5] = need2 - cum; sh[6] = 0; sh[7] = 0;
  }
  __syncthreads();
  unsigned Tkey = (pref2 << 10) | (unsigned)sh[4];
  int needEq = sh[5];
  for (int i = t; i < Nc; i += 1024){
    float v = cand_vals[i];
    unsigned k = __float_as_uint(v);
    if (k > Tkey){
      int p = atomicAdd(&sh[6], 1);
      if (p < LIMIT){ sel_vals[p] = v; sel_idx[p] = cand_idx[i]; }
    } else if (k == Tkey){
      int p = atomicAdd(&sh[7], 1);
      if (p < 1024) eqidx[p] = cand_idx[i];
    }
  }
  __syncthreads();
  if (t == 0){
    int nAbove = sh[6]; if (nAbove > LIMIT) nAbove = LIMIT;
    int neq = sh[7]; if (neq > 1024) neq = 1024;
    int take = needEq; if (take > neq) take = neq; if (nAbove + take > LIMIT) take = LIMIT - nAbove;
    // tie-break: smallest flat index first (matches jax.lax.top_k)
    for (int j = 0; j < take; j++){
      int mi = j;
      for (int l = j+1; l < neq; l++) if (eqidx[l] < eqidx[mi]) mi = l;
      int tmp = eqidx[j]; eqidx[j] = eqidx[mi]; eqidx[mi] = tmp;
      sel_vals[nAbove + j] = __uint_as_float(Tkey);
      sel_idx[nAbove + j] = eqidx[j];
    }
    for (int j = nAbove + take; j < LIMIT; j++){ sel_vals[j] = 0.f; sel_idx[j] = 0; }
  }
}

// ---------------- K3e: gather correspondence points ---------------------------
__global__ void k3e_kernel(const int* __restrict__ sel_idx, const float* __restrict__ refp,
                           const float* __restrict__ srcp, float* sel_ref, float* sel_src){
  int p = blockIdx.x*blockDim.x + threadIdx.x;
  if (p >= LIMIT) return;
  int idx = sel_idx[p];
  int b = idx >> 14, r = (idx >> 7) & 127, s = idx & 127;
  for (int c = 0; c < 3; c++){
    sel_ref[p*3+c] = refp[(b*NN+r)*3+c];
    sel_src[p*3+c] = srcp[(b*NN+s)*3+c];
  }
}

// ---------------- K4: inlier counts per batch ---------------------------------
__global__ __launch_bounds__(256) void k4_kernel(
    const float* __restrict__ localT, const float* __restrict__ sel_vals,
    const float* __restrict__ sel_ref, const float* __restrict__ sel_src,
    const int* __restrict__ pcount, int* counts)
{
  __shared__ int ired[4];
  int b = blockIdx.x, t = threadIdx.x;
  const float* T = &localT[b*12];
  float R00=T[0],R01=T[1],R02=T[2],R10=T[3],R11=T[4],R12=T[5],R20=T[6],R21=T[7],R22=T[8];
  float tx=T[9], ty=T[10], tz=T[11];
  int c = 0;
  for (int p = t; p < LIMIT; p += 256){
    float v = sel_vals[p];
    if (!(v > 0.f)) continue;
    float sx=sel_src[p*3], sy=sel_src[p*3+1], sz=sel_src[p*3+2];
    float rx=sel_ref[p*3], ry=sel_ref[p*3+1], rz=sel_ref[p*3+2];
    float ax = R00*sx + R01*sy + R02*sz + tx;
    float ay = R10*sx + R11*sy + R12*sz + ty;
    float az = R20*sx + R21*sy + R22*sz + tz;
    float dx = rx-ax, dy = ry-ay, dz = rz-az;
    if (sqrtf(dx*dx + dy*dy + dz*dz) < 0.1f) c++;
  }
  int lane = t & 63, wv = t >> 6;
  for (int off = 32; off > 0; off >>= 1) c += __shfl_down(c, off);
  if (lane == 0) ired[wv] = c;
  __syncthreads();
  if (t == 0) counts[b] = (pcount[b] >= 3) ? (ired[0]+ired[1]+ired[2]+ired[3]) : -1;
}

// ---------------- K5: argmax best + 5x weighted Procrustes --------------------
__global__ __launch_bounds__(256) void k5_kernel(
    const int* __restrict__ counts, const float* __restrict__ localT,
    const float* __restrict__ sel_vals, const float* __restrict__ sel_ref,
    const float* __restrict__ sel_src, float* out)
{
  __shared__ double dred[4][16];
  __shared__ long long lred[4];
  __shared__ double RT[12];
  __shared__ int sbest;
  int t = threadIdx.x, lane = t & 63, wv = t >> 6;
  long long key = (long long)0x8000000000000000LL;
  for (int b = t; b < BB; b += 256){
    long long kk = ((long long)(counts[b] + 2) << 32) | (long long)(511 - b);
    if (kk > key) key = kk;
  }
  for (int off = 32; off > 0; off >>= 1){ long long o = __shfl_down(key, off); if (o > key) key = o; }
  if (lane == 0) lred[wv] = key;
  __syncthreads();
  if (t == 0){
    long long m = lred[0];
    for (int w = 1; w < 4; w++) if (lred[w] > m) m = lred[w];
    sbest = 511 - (int)(m & 0xFFFFFFFFLL);
  }
  __syncthreads();
  if (t < 12) RT[t] = (double)localT[sbest*12 + t];
  __syncthreads();

  for (int iter = 0; iter < 5; iter++){
    float R00=(float)RT[0],R01=(float)RT[1],R02=(float)RT[2];
    float R10=(float)RT[3],R11=(float)RT[4],R12=(float)RT[5];
    float R20=(float)RT[6],R21=(float)RT[7],R22=(float)RT[8];
    float tx=(float)RT[9], ty=(float)RT[10], tz=(float)RT[11];
    double a[16];
    for (int k = 0; k < 16; k++) a[k] = 0.0;
    for (int p = t; p < LIMIT; p += 256){
      float v = sel_vals[p];
      if (!(v > 0.f)) continue;
      float sx=sel_src[p*3], sy=sel_src[p*3+1], sz=sel_src[p*3+2];
      float rx=sel_ref[p*3], ry=sel_ref[p*3+1], rz=sel_ref[p*3+2];
      float ax = R00*sx + R01*sy + R02*sz + tx;
      float ay = R10*sx + R11*sy + R12*sz + ty;
      float az = R20*sx + R21*sy + R22*sz + tz;
      float dx = rx-ax, dy = ry-ay, dz = rz-az;
      if (sqrtf(dx*dx + dy*dy + dz*dz) < 0.1f){
        double w = (double)v;
        a[0] += w;
        a[1] += w*sx; a[2] += w*sy; a[3] += w*sz;
        a[4] += w*rx; a[5] += w*ry; a[6] += w*rz;
        a[7]  += w*sx*rx; a[8]  += w*sx*ry; a[9]  += w*sx*rz;
        a[10] += w*sy*rx; a[11] += w*sy*ry; a[12] += w*sy*rz;
        a[13] += w*sz*rx; a[14] += w*sz*ry; a[15] += w*sz*rz;
      }
    }
    for (int k = 0; k < 16; k++){
      double v = a[k];
      for (int off = 32; off > 0; off >>= 1) v += __shfl_down(v, off);
      if (lane == 0) dred[wv][k] = v;
    }
    __syncthreads();
    if (t == 0){
      double tot[16];
      for (int k = 0; k < 16; k++) tot[k] = dred[0][k]+dred[1][k]+dred[2][k]+dred[3][k];
      double W = tot[0], denom = W + 1e-5, s = W / denom;
      double scv[3] = { tot[1]/denom, tot[2]/denom, tot[3]/denom };
      double rcv[3] = { tot[4]/denom, tot[5]/denom, tot[6]/denom };
      double H[3][3];
      for (int c = 0; c < 3; c++)
        for (int d = 0; d < 3; d++)
          H[c][d] = tot[7 + c*3 + d]/denom - (2.0 - s)*scv[c]*rcv[d];
      double R[3][3];
      kabsch_rot(H, R);
      for (int i = 0; i < 3; i++) for (int j = 0; j < 3; j++) RT[i*3+j] = R[i][j];
      for (int i = 0; i < 3; i++)
        RT[9+i] = rcv[i] - (R[i][0]*scv[0] + R[i][1]*scv[1] + R[i][2]*scv[2]);
    }
    __syncthreads();
  }
  if (t == 0){
    out[0]=(float)RT[0];  out[1]=(float)RT[1];  out[2]=(float)RT[2];  out[3]=(float)RT[9];
    out[4]=(float)RT[3];  out[5]=(float)RT[4];  out[6]=(float)RT[5];  out[7]=(float)RT[10];
    out[8]=(float)RT[6];  out[9]=(float)RT[7];  out[10]=(float)RT[8]; out[11]=(float)RT[11];
    out[12]=0.f; out[13]=0.f; out[14]=0.f; out[15]=1.f;
  }
}

// ---------------- host launcher -----------------------------------------------
extern "C" void kernel_launch(void* const* d_in, const int* in_sizes, int n_in,
                              void* d_out, int out_size, void* d_ws, size_t ws_size,
                              hipStream_t stream){
  const float* score = (const float*)d_in[0];
  const float* refp  = (const float*)d_in[1];
  const float* srcp  = (const float*)d_in[2];
  const void*  rmask = d_in[3];
  const void*  smask = d_in[4];

  char* ws = (char*)d_ws;
  size_t off = 0;
  int* hdr = (int*)(ws + off);            off += 256;
  float* cand_vals = (float*)(ws + off);  off += (size_t)CAND_CAP*4;
  int* cand_idx = (int*)(ws + off);       off += (size_t)CAND_CAP*4;
  float* Hsr = (float*)(ws + off);        off += (size_t)BB*15*4;
  int* pcount = (int*)(ws + off);         off += (size_t)BB*4;
  float* localT = (float*)(ws + off);     off += (size_t)BB*12*4;
  float* sel_vals = (float*)(ws + off);   off += (size_t)LIMIT*4;
  int* sel_idx = (int*)(ws + off);        off += (size_t)LIMIT*4;
  float* sel_ref = (float*)(ws + off);    off += (size_t)LIMIT*3*4;
  float* sel_src = (float*)(ws + off);    off += (size_t)LIMIT*3*4;
  int* counts = (int*)(ws + off);         off += (size_t)BB*4;

  hipMemsetAsync(ws, 0, 256, stream);
  hipLaunchKernelGGL(kmode_kernel, dim3(1), dim3(1), 0, stream, rmask, hdr);
  hipLaunchKernelGGL(k1_kernel, dim3(BB), dim3(NN), 0, stream,
                     score, refp, srcp, rmask, smask, hdr, cand_vals, cand_idx, Hsr, pcount);
  hipLaunchKernelGGL(k2_kernel, dim3(2), dim3(256), 0, stream, Hsr, localT);
  hipLaunchKernelGGL(k3_kernel, dim3(1), dim3(1024), 0, stream,
                     hdr, cand_vals, cand_idx, sel_vals, sel_idx);
  hipLaunchKernelGGL(k3e_kernel, dim3(8), dim3(256), 0, stream,
                     sel_idx, refp, srcp, sel_ref, sel_src);
  hipLaunchKernelGGL(k4_kernel, dim3(BB), dim3(256), 0, stream,
                     localT, sel_vals, sel_ref, sel_src, pcount, counts);
  hipLaunchKernelGGL(k5_kernel, dim3(1), dim3(256), 0, stream,
                     counts, localT, sel_vals, sel_ref, sel_src, (float*)d_out);
}

// Round 2
// 318.227 us; speedup vs baseline: 4.1569x; 4.1569x over previous
//
#include <hip/hip_runtime.h>
#include <math.h>

#define BB 512
#define NN 128
#define CAND_CAP (512*384)
#define LIMIT 2048
#define EQCAP 16384
#define NBIN1 4096

// ---------------- mask decode (int32 / byte / float32 robustness) -------------
__device__ inline bool read_mask(const void* p, int i, int mode){
  if (mode == 0) return ((const int*)p)[i] != 0;
  if (mode == 1) return ((const unsigned char*)p)[i] != 0;
  return ((const float*)p)[i] != 0.0f;
}

__global__ void kmode_kernel(const void* m, int* hdr){
  int t = threadIdx.x;
  unsigned v = ((const unsigned*)m)[t];
  bool n01 = !(v == 0u || v == 1u);
  bool nf  = !(v == 0u || v == 0x3F800000u);
  unsigned long long b01 = __ballot(n01), bf = __ballot(nf);
  if (t == 0) hdr[3] = (b01 == 0ull) ? 0 : ((bf == 0ull) ? 2 : 1);
}

// ---------------- K1: exp, mutual top-3, candidates, per-batch H/sc/rc --------
__global__ __launch_bounds__(128) void k1_kernel(
    const float* __restrict__ score, const float* __restrict__ refp,
    const float* __restrict__ srcp, const void* __restrict__ rmaskp,
    const void* __restrict__ smaskp, int* hdr, float* cand_vals, int* cand_idx,
    float* Hsr, int* pcount)
{
  __shared__ float tile[NN*NN];      // 64 KB exp-score tile
  __shared__ float t3col[NN];
  __shared__ float smaskv[NN];
  __shared__ float srcsh[NN*3];
  __shared__ float red[2][17];
  __shared__ int wsum[2];
  __shared__ int basesh;
  const int b = blockIdx.x, t = threadIdx.x;
  const int mode = hdr[3];

  // coalesced load + exp
  const float4* s4 = (const float4*)(score + (size_t)b*NN*NN);
  float4* t4 = (float4*)tile;
  for (int j = t; j < NN*NN/4; j += NN){
    float4 v = s4[j];
    v.x = expf(v.x); v.y = expf(v.y); v.z = expf(v.z); v.w = expf(v.w);
    t4[j] = v;
  }
  smaskv[t] = read_mask(smaskp, b*NN + t, mode) ? 1.f : 0.f;
  const float rm = read_mask(rmaskp, b*NN + t, mode) ? 1.f : 0.f;
  const float rx = refp[(b*NN+t)*3+0], ry = refp[(b*NN+t)*3+1], rz = refp[(b*NN+t)*3+2];
  srcsh[t*3+0] = srcp[(b*NN+t)*3+0];
  srcsh[t*3+1] = srcp[(b*NN+t)*3+1];
  srcsh[t*3+2] = srcp[(b*NN+t)*3+2];
  __syncthreads();

  // column top-3 (thread t owns column t): 2-way bank alias = free
  float c1=-1e30f, c2=-1e30f, c3=-1e30f;
  for (int n = 0; n < NN; n++){
    float v = tile[n*NN + t];
    if (v > c1){ c3=c2; c2=c1; c1=v; } else if (v > c2){ c3=c2; c2=v; } else if (v > c3){ c3=v; }
  }
  t3col[t] = c3;
  // row top-3 (thread t owns row t), rotated to avoid 64-way conflicts
  float r1=-1e30f, r2=-1e30f, r3v=-1e30f;
  for (int i = 0; i < NN; i++){
    int m = (t + i) & (NN - 1);
    float v = tile[t*NN + m];
    if (v > r1){ r3v=r2; r2=r1; r1=v; } else if (v > r2){ r3v=r2; r2=v; } else if (v > r3v){ r3v=v; }
  }
  __syncthreads();

  // masked pass: keep mutual-top-3 & >CONF & masks; per-thread <=3 candidates
  float wr = 0.f, p0 = 0.f, p1 = 0.f, p2 = 0.f, cntf = 0.f;
  float kv[3]; int km[3]; int cnt = 0;
  for (int i = 0; i < NN; i++){
    int m = (t + i) & (NN - 1);
    float v = tile[t*NN + m];
    bool keep = (rm > 0.f) && (smaskv[m] > 0.f) && (v > 0.05f) && (v >= r3v) && (v >= t3col[m]);
    if (keep){
      cntf += 1.f; wr += v;
      p0 += v*srcsh[m*3+0]; p1 += v*srcsh[m*3+1]; p2 += v*srcsh[m*3+2];
      if (cnt < 3){ kv[cnt] = v; km[cnt] = m; cnt++; }
    } else {
      tile[t*NN + m] = 0.f;
    }
  }
  // block-wide exclusive scan of cnt -> single atomic per block
  int lane = t & 63, wv = t >> 6;
  int x = cnt;
  for (int off = 1; off < 64; off <<= 1){ int y = __shfl_up(x, off); if (lane >= off) x += y; }
  if (lane == 63) wsum[wv] = x;
  __syncthreads();
  if (t == 0) basesh = atomicAdd(&hdr[0], wsum[0] + wsum[1]);
  __syncthreads();
  int base = basesh + (wv == 1 ? wsum[0] : 0) + (x - cnt);
  for (int j = 0; j < cnt; j++){
    int pos = base + j;
    if (pos < CAND_CAP){ cand_vals[pos] = kv[j]; cand_idx[pos] = (b<<14)|(t<<7)|km[j]; }
  }
  __syncthreads();

  // column sums of masked values
  float wc = 0.f;
  for (int n = 0; n < NN; n++) wc += tile[n*NN + t];
  float sx = srcsh[t*3+0], sy = srcsh[t*3+1], sz = srcsh[t*3+2];

  float q[17];
  q[0]=cntf; q[1]=wr;
  q[2]=wr*rx; q[3]=wr*ry; q[4]=wr*rz;       // rc numerator
  q[5]=wc*sx; q[6]=wc*sy; q[7]=wc*sz;       // sc numerator
  q[8]=p0*rx;  q[9]=p0*ry;  q[10]=p0*rz;    // M^[c][d] = sum p_c * ref_d
  q[11]=p1*rx; q[12]=p1*ry; q[13]=p1*rz;
  q[14]=p2*rx; q[15]=p2*ry; q[16]=p2*rz;
  for (int k = 0; k < 17; k++){
    float v = q[k];
    for (int off = 32; off > 0; off >>= 1) v += __shfl_down(v, off);
    if (lane == 0) red[wv][k] = v;
  }
  __syncthreads();
  if (t == 0){
    float tot[17];
    for (int k = 0; k < 17; k++) tot[k] = red[0][k] + red[1][k];
    float Wm = tot[1];
    float denom = Wm + 1e-5f;
    float s = Wm / denom;
    float rcv[3] = { tot[2]/denom, tot[3]/denom, tot[4]/denom };
    float scv[3] = { tot[5]/denom, tot[6]/denom, tot[7]/denom };
    float* o = &Hsr[b*15];
    for (int c = 0; c < 3; c++)
      for (int d = 0; d < 3; d++)
        o[c*3+d] = tot[8 + c*3 + d]/denom - (2.f - s)*scv[c]*rcv[d];
    o[9]=scv[0]; o[10]=scv[1]; o[11]=scv[2];
    o[12]=rcv[0]; o[13]=rcv[1]; o[14]=rcv[2];
    pcount[b] = (int)(tot[0] + 0.5f);
  }
}

// ---------------- Kabsch rotation from 3x3 covariance (double Jacobi) ---------
__device__ void kabsch_rot(const double H[3][3], double R[3][3]){
  double S[3][3];
  for (int i = 0; i < 3; i++)
    for (int j = 0; j < 3; j++){
      double a = 0.0;
      for (int k = 0; k < 3; k++) a += H[k][i]*H[k][j];
      S[i][j] = a;
    }
  double V[3][3] = {{1,0,0},{0,1,0},{0,0,1}};
  for (int sweep = 0; sweep < 30; sweep++){
    double off  = S[0][1]*S[0][1] + S[0][2]*S[0][2] + S[1][2]*S[1][2];
    double base = S[0][0]*S[0][0] + S[1][1]*S[1][1] + S[2][2]*S[2][2];
    if (off <= base*1e-28 + 1e-280) break;
    for (int p = 0; p < 2; p++)
      for (int q = p+1; q < 3; q++){
        double apq = S[p][q];
        if (fabs(apq) <= 1e-280) continue;
        double tau = (S[q][q] - S[p][p]) / (2.0*apq);
        double tt  = (tau >= 0.0 ? 1.0 : -1.0) / (fabs(tau) + sqrt(1.0 + tau*tau));
        double c = 1.0 / sqrt(1.0 + tt*tt), s = tt*c;
        for (int k = 0; k < 3; k++){ double a=S[k][p], b2=S[k][q]; S[k][p]=c*a-s*b2; S[k][q]=s*a+c*b2; }
        for (int k = 0; k < 3; k++){ double a=S[p][k], b2=S[q][k]; S[p][k]=c*a-s*b2; S[q][k]=s*a+c*b2; }
        for (int k = 0; k < 3; k++){ double a=V[k][p], b2=V[k][q]; V[k][p]=c*a-s*b2; V[k][q]=s*a+c*b2; }
      }
  }
  double lam[3] = { S[0][0], S[1][1], S[2][2] };
  int o0=0,o1=1,o2=2;
  if (lam[o0] < lam[o1]){ int x=o0;o0=o1;o1=x; }
  if (lam[o0] < lam[o2]){ int x=o0;o0=o2;o2=x; }
  if (lam[o1] < lam[o2]){ int x=o1;o1=o2;o2=x; }
  double v0[3]={V[0][o0],V[1][o0],V[2][o0]};
  double v1[3]={V[0][o1],V[1][o1],V[2][o1]};
  double v2[3]={V[0][o2],V[1][o2],V[2][o2]};
  double sig0 = sqrt(fmax(lam[o0], 0.0));
  if (!(sig0 > 1e-20)){
    for (int i = 0; i < 3; i++) for (int j = 0; j < 3; j++) R[i][j] = (i==j) ? 1.0 : 0.0;
    return;
  }
  double u0[3],u1[3],u2[3];
  for (int i = 0; i < 3; i++) u0[i] = H[i][0]*v0[0] + H[i][1]*v0[1] + H[i][2]*v0[2];
  double n0 = sqrt(u0[0]*u0[0]+u0[1]*u0[1]+u0[2]*u0[2]);
  for (int i = 0; i < 3; i++) u0[i] /= n0;
  for (int i = 0; i < 3; i++) u1[i] = H[i][0]*v1[0] + H[i][1]*v1[1] + H[i][2]*v1[2];
  double dp = u1[0]*u0[0]+u1[1]*u0[1]+u1[2]*u0[2];
  for (int i = 0; i < 3; i++) u1[i] -= dp*u0[i];
  double n1 = sqrt(u1[0]*u1[0]+u1[1]*u1[1]+u1[2]*u1[2]);
  if (n1 > sig0*1e-10){
    for (int i = 0; i < 3; i++) u1[i] /= n1;
  } else {
    int k = (fabs(u0[0])<=fabs(u0[1]) && fabs(u0[0])<=fabs(u0[2])) ? 0 : ((fabs(u0[1])<=fabs(u0[2])) ? 1 : 2);
    double e[3] = {0,0,0}; e[k] = 1.0;
    double d2 = e[0]*u0[0]+e[1]*u0[1]+e[2]*u0[2];
    for (int i = 0; i < 3; i++) u1[i] = e[i] - d2*u0[i];
    double nn = sqrt(u1[0]*u1[0]+u1[1]*u1[1]+u1[2]*u1[2]);
    for (int i = 0; i < 3; i++) u1[i] /= nn;
  }
  u2[0] = u0[1]*u1[2] - u0[2]*u1[1];
  u2[1] = u0[2]*u1[0] - u0[0]*u1[2];
  u2[2] = u0[0]*u1[1] - u0[1]*u1[0];
  double cx = v1[1]*v2[2] - v1[2]*v2[1];
  double cy = v1[2]*v2[0] - v1[0]*v2[2];
  double cz = v1[0]*v2[1] - v1[1]*v2[0];
  double detV = v0[0]*cx + v0[1]*cy + v0[2]*cz;  // det(U)=+1 by construction
  double dd = (detV >= 0.0) ? 1.0 : -1.0;
  for (int i = 0; i < 3; i++)
    for (int j = 0; j < 3; j++)
      R[i][j] = v0[i]*u0[j] + v1[i]*u1[j] + dd*v2[i]*u2[j];
}

// ---------------- K2: per-batch local transforms ------------------------------
__global__ void k2_kernel(const float* __restrict__ Hsr, float* __restrict__ localT){
  int b = blockIdx.x*blockDim.x + threadIdx.x;
  if (b >= BB) return;
  const float* o = &Hsr[b*15];
  double H[3][3];
  for (int c = 0; c < 3; c++) for (int d = 0; d < 3; d++) H[c][d] = (double)o[c*3+d];
  double sc[3] = { o[9], o[10], o[11] }, rc[3] = { o[12], o[13], o[14] };
  double R[3][3];
  kabsch_rot(H, R);
  float* T = &localT[b*12];
  for (int i = 0; i < 3; i++) for (int j = 0; j < 3; j++) T[i*3+j] = (float)R[i][j];
  for (int i = 0; i < 3; i++)
    T[9+i] = (float)(rc[i] - (R[i][0]*sc[0] + R[i][1]*sc[1] + R[i][2]*sc[2]));
}

// ---------------- K3a: grid histogram of top-12 key bits ----------------------
__global__ __launch_bounds__(256) void k3a_kernel(
    const int* hdr, const float* __restrict__ cand_vals, int* hist)
{
  __shared__ int lh[NBIN1];
  int t = threadIdx.x;
  int Nc = hdr[0]; if (Nc > CAND_CAP) Nc = CAND_CAP;
  for (int j = t; j < NBIN1; j += 256) lh[j] = 0;
  __syncthreads();
  for (int i = blockIdx.x*256 + t; i < Nc; i += gridDim.x*256)
    atomicAdd(&lh[__float_as_uint(cand_vals[i]) >> 20], 1);
  __syncthreads();
  for (int j = t; j < NBIN1; j += 256)
    if (lh[j]) atomicAdd(&hist[j], lh[j]);
}

// ---------------- K3b: find boundary bin ------------------------------------
__global__ __launch_bounds__(256) void k3b_kernel(int* hdr, const int* hist){
  __shared__ int chunk[256];
  int t = threadIdx.x;
  int s = 0;
  for (int j = 0; j < 16; j++) s += hist[t*16 + j];
  chunk[t] = s;
  __syncthreads();
  if (t == 0){
    int Nc = hdr[0]; if (Nc > CAND_CAP) Nc = CAND_CAP;
    if (Nc <= LIMIT){ hdr[4] = -1; hdr[5] = 0; }
    else {
      int cum = 0, c = 255;
      for (; c >= 0; c--){ if (cum + chunk[c] >= LIMIT) break; cum += chunk[c]; }
      int bin1 = 0, need = 0;
      for (int b2 = c*16 + 15; b2 >= c*16; b2--){
        if (cum + hist[b2] >= LIMIT){ bin1 = b2; need = LIMIT - cum; break; }
        cum += hist[b2];
      }
      hdr[4] = bin1; hdr[5] = need;
    }
  }
}

// ---------------- K3c: partition above-bin / equal-bin ------------------------
__global__ __launch_bounds__(256) void k3c_kernel(
    int* hdr, const float* __restrict__ cand_vals, const int* __restrict__ cand_idx,
    float* sel_vals, int* sel_idx, float* eq_vals, int* eq_idx)
{
  int Nc = hdr[0]; if (Nc > CAND_CAP) Nc = CAND_CAP;
  int bin1 = hdr[4];
  for (int i = blockIdx.x*256 + threadIdx.x; i < Nc; i += gridDim.x*256){
    float v = cand_vals[i];
    if (bin1 < 0){
      int p = atomicAdd(&hdr[2], 1);
      if (p < LIMIT){ sel_vals[p] = v; sel_idx[p] = cand_idx[i]; }
      continue;
    }
    int bin = (int)(__float_as_uint(v) >> 20);
    if (bin > bin1){
      int p = atomicAdd(&hdr[2], 1);
      if (p < LIMIT){ sel_vals[p] = v; sel_idx[p] = cand_idx[i]; }
    } else if (bin == bin1){
      int q = atomicAdd(&hdr[1], 1);
      if (q < EQCAP){ eq_vals[q] = v; eq_idx[q] = cand_idx[i]; }
    }
  }
}

// ---------------- K3d: refine within boundary bin -----------------------------
__global__ __launch_bounds__(1024) void k3d_kernel(
    const int* hdr, const float* __restrict__ eq_vals, const int* __restrict__ eq_idx,
    float* sel_vals, int* sel_idx)
{
  __shared__ int hist[2048];
  __shared__ int sh[8];
  __shared__ int eqsh[2048];
  int t = threadIdx.x;
  int bin1 = hdr[4];
  int nAbove = hdr[2]; if (nAbove > LIMIT) nAbove = LIMIT;
  if (bin1 < 0){
    for (int i = t; i < LIMIT; i += 1024)
      if (i >= nAbove){ sel_vals[i] = 0.f; sel_idx[i] = 0; }
    return;
  }
  int neq = hdr[1]; if (neq > EQCAP) neq = EQCAP;
  int need = hdr[5];
  if (need >= neq){
    for (int i = t; i < neq; i += 1024){ sel_vals[nAbove+i] = eq_vals[i]; sel_idx[nAbove+i] = eq_idx[i]; }
    for (int i = t; i < LIMIT; i += 1024)
      if (i >= nAbove + neq){ sel_vals[i] = 0.f; sel_idx[i] = 0; }
    return;
  }
  // radix on low-20 bits: pass A bits 19..9 (2048 bins)
  for (int i = t; i < 2048; i += 1024) hist[i] = 0;
  __syncthreads();
  for (int i = t; i < neq; i += 1024)
    atomicAdd(&hist[(__float_as_uint(eq_vals[i]) >> 9) & 0x7FF], 1);
  __syncthreads();
  if (t == 0){
    int cum = 0, bin = 0;
    for (int j = 2047; j >= 0; j--){ if (cum + hist[j] >= need){ bin = j; break; } cum += hist[j]; }
    sh[0] = bin; sh[1] = need - cum;
  }
  __syncthreads();
  int binA = sh[0], need2 = sh[1];
  // pass B bits 8..0 (512 bins)
  for (int i = t; i < 2048; i += 1024) hist[i] = 0;
  __syncthreads();
  for (int i = t; i < neq; i += 1024){
    unsigned k = __float_as_uint(eq_vals[i]);
    if ((int)((k >> 9) & 0x7FF) == binA) atomicAdd(&hist[k & 0x1FF], 1);
  }
  __syncthreads();
  if (t == 0){
    int cum = 0, bin = 0;
    for (int j = 511; j >= 0; j--){ if (cum + hist[j] >= need2){ bin = j; break; } cum += hist[j]; }
    sh[2] = bin; sh[4] = 0; sh[5] = 0;
  }
  __syncthreads();
  unsigned Tlow = (((unsigned)binA) << 9) | (unsigned)sh[2];
  unsigned Tkey = (((unsigned)bin1) << 20) | Tlow;
  for (int i = t; i < neq; i += 1024){
    unsigned k = __float_as_uint(eq_vals[i]);
    unsigned k20 = k & 0xFFFFF;
    if (k20 > Tlow){
      int p = atomicAdd(&sh[4], 1);
      sel_vals[nAbove + p] = eq_vals[i]; sel_idx[nAbove + p] = eq_idx[i];
    } else if (k20 == Tlow){
      int q = atomicAdd(&sh[5], 1);
      if (q < 2048) eqsh[q] = eq_idx[i];
    }
  }
  __syncthreads();
  if (t == 0){
    int na2 = sh[4];
    int ne2 = sh[5]; if (ne2 > 2048) ne2 = 2048;
    int take = need - na2; if (take > ne2) take = ne2; if (take < 0) take = 0;
    if (nAbove + na2 + take > LIMIT) take = LIMIT - nAbove - na2;
    // tie-break: smallest flat index first (matches jax.lax.top_k)
    int* eq2 = eqsh;
    for (int j = 0; j < take; j++){
      int mi = j;
      for (int l = j+1; l < ne2; l++) if (eq2[l] < eq2[mi]) mi = l;
      int tmp = eq2[j]; eq2[j] = eq2[mi]; eq2[mi] = tmp;
      sel_vals[nAbove + na2 + j] = __uint_as_float(Tkey);
      sel_idx[nAbove + na2 + j] = eq2[j];
    }
    for (int j = nAbove + na2 + take; j < LIMIT; j++){ sel_vals[j] = 0.f; sel_idx[j] = 0; }
  }
}

// ---------------- K3e: gather correspondence points ---------------------------
__global__ void k3e_kernel(const int* __restrict__ sel_idx, const float* __restrict__ refp,
                           const float* __restrict__ srcp, float* sel_ref, float* sel_src){
  int p = blockIdx.x*blockDim.x + threadIdx.x;
  if (p >= LIMIT) return;
  int idx = sel_idx[p];
  int b = idx >> 14, r = (idx >> 7) & 127, s = idx & 127;
  for (int c = 0; c < 3; c++){
    sel_ref[p*3+c] = refp[(b*NN+r)*3+c];
    sel_src[p*3+c] = srcp[(b*NN+s)*3+c];
  }
}

// ---------------- K4: inlier counts per batch ---------------------------------
__global__ __launch_bounds__(256) void k4_kernel(
    const float* __restrict__ localT, const float* __restrict__ sel_vals,
    const float* __restrict__ sel_ref, const float* __restrict__ sel_src,
    const int* __restrict__ pcount, int* counts)
{
  __shared__ int ired[4];
  int b = blockIdx.x, t = threadIdx.x;
  const float* T = &localT[b*12];
  float R00=T[0],R01=T[1],R02=T[2],R10=T[3],R11=T[4],R12=T[5],R20=T[6],R21=T[7],R22=T[8];
  float tx=T[9], ty=T[10], tz=T[11];
  int c = 0;
  for (int p = t; p < LIMIT; p += 256){
    float v = sel_vals[p];
    if (!(v > 0.f)) continue;
    float sx=sel_src[p*3], sy=sel_src[p*3+1], sz=sel_src[p*3+2];
    float rx=sel_ref[p*3], ry=sel_ref[p*3+1], rz=sel_ref[p*3+2];
    float ax = R00*sx + R01*sy + R02*sz + tx;
    float ay = R10*sx + R11*sy + R12*sz + ty;
    float az = R20*sx + R21*sy + R22*sz + tz;
    float dx = rx-ax, dy = ry-ay, dz = rz-az;
    if (sqrtf(dx*dx + dy*dy + dz*dz) < 0.1f) c++;
  }
  int lane = t & 63, wv = t >> 6;
  for (int off = 32; off > 0; off >>= 1) c += __shfl_down(c, off);
  if (lane == 0) ired[wv] = c;
  __syncthreads();
  if (t == 0) counts[b] = (pcount[b] >= 3) ? (ired[0]+ired[1]+ired[2]+ired[3]) : -1;
}

// ---------------- K5: argmax best + 5x weighted Procrustes --------------------
__global__ __launch_bounds__(1024) void k5_kernel(
    const int* __restrict__ counts, const float* __restrict__ localT,
    const float* __restrict__ sel_vals, const float* __restrict__ sel_ref,
    const float* __restrict__ sel_src, float* out)
{
  __shared__ double dred[16][16];
  __shared__ long long lred[16];
  __shared__ double RT[12];
  __shared__ int sbest;
  int t = threadIdx.x, lane = t & 63, wv = t >> 6;
  long long key = (long long)0x8000000000000000LL;
  for (int b = t; b < BB; b += 1024){
    long long kk = ((long long)(counts[b] + 2) << 32) | (long long)(511 - b);
    if (kk > key) key = kk;
  }
  for (int off = 32; off > 0; off >>= 1){ long long o = __shfl_down(key, off); if (o > key) key = o; }
  if (lane == 0) lred[wv] = key;
  __syncthreads();
  if (t == 0){
    long long m = lred[0];
    for (int w = 1; w < 16; w++) if (lred[w] > m) m = lred[w];
    sbest = 511 - (int)(m & 0xFFFFFFFFLL);
  }
  __syncthreads();
  if (t < 12) RT[t] = (double)localT[sbest*12 + t];
  __syncthreads();

  for (int iter = 0; iter < 5; iter++){
    float R00=(float)RT[0],R01=(float)RT[1],R02=(float)RT[2];
    float R10=(float)RT[3],R11=(float)RT[4],R12=(float)RT[5];
    float R20=(float)RT[6],R21=(float)RT[7],R22=(float)RT[8];
    float tx=(float)RT[9], ty=(float)RT[10], tz=(float)RT[11];
    double a[16];
    for (int k = 0; k < 16; k++) a[k] = 0.0;
    for (int p = t; p < LIMIT; p += 1024){
      float v = sel_vals[p];
      if (!(v > 0.f)) continue;
      float sx=sel_src[p*3], sy=sel_src[p*3+1], sz=sel_src[p*3+2];
      float rx=sel_ref[p*3], ry=sel_ref[p*3+1], rz=sel_ref[p*3+2];
      float ax = R00*sx + R01*sy + R02*sz + tx;
      float ay = R10*sx + R11*sy + R12*sz + ty;
      float az = R20*sx + R21*sy + R22*sz + tz;
      float dx = rx-ax, dy = ry-ay, dz = rz-az;
      if (sqrtf(dx*dx + dy*dy + dz*dz) < 0.1f){
        double w = (double)v;
        a[0] += w;
        a[1] += w*sx; a[2] += w*sy; a[3] += w*sz;
        a[4] += w*rx; a[5] += w*ry; a[6] += w*rz;
        a[7]  += w*sx*rx; a[8]  += w*sx*ry; a[9]  += w*sx*rz;
        a[10] += w*sy*rx; a[11] += w*sy*ry; a[12] += w*sy*rz;
        a[13] += w*sz*rx; a[14] += w*sz*ry; a[15] += w*sz*rz;
      }
    }
    for (int k = 0; k < 16; k++){
      double v = a[k];
      for (int off = 32; off > 0; off >>= 1) v += __shfl_down(v, off);
      if (lane == 0) dred[wv][k] = v;
    }
    __syncthreads();
    if (t == 0){
      double tot[16];
      for (int k = 0; k < 16; k++){
        double s2 = 0.0;
        for (int w = 0; w < 16; w++) s2 += dred[w][k];
        tot[k] = s2;
      }
      double W = tot[0], denom = W + 1e-5, s = W / denom;
      double scv[3] = { tot[1]/denom, tot[2]/denom, tot[3]/denom };
      double rcv[3] = { tot[4]/denom, tot[5]/denom, tot[6]/denom };
      double H[3][3];
      for (int c = 0; c < 3; c++)
        for (int d = 0; d < 3; d++)
          H[c][d] = tot[7 + c*3 + d]/denom - (2.0 - s)*scv[c]*rcv[d];
      double R[3][3];
      kabsch_rot(H, R);
      for (int i = 0; i < 3; i++) for (int j = 0; j < 3; j++) RT[i*3+j] = R[i][j];
      for (int i = 0; i < 3; i++)
        RT[9+i] = rcv[i] - (R[i][0]*scv[0] + R[i][1]*scv[1] + R[i][2]*scv[2]);
    }
    __syncthreads();
  }
  if (t == 0){
    out[0]=(float)RT[0];  out[1]=(float)RT[1];  out[2]=(float)RT[2];  out[3]=(float)RT[9];
    out[4]=(float)RT[3];  out[5]=(float)RT[4];  out[6]=(float)RT[5];  out[7]=(float)RT[10];
    out[8]=(float)RT[6];  out[9]=(float)RT[7];  out[10]=(float)RT[8]; out[11]=(float)RT[11];
    out[12]=0.f; out[13]=0.f; out[14]=0.f; out[15]=1.f;
  }
}

// ---------------- host launcher -----------------------------------------------
extern "C" void kernel_launch(void* const* d_in, const int* in_sizes, int n_in,
                              void* d_out, int out_size, void* d_ws, size_t ws_size,
                              hipStream_t stream){
  const float* score = (const float*)d_in[0];
  const float* refp  = (const float*)d_in[1];
  const float* srcp  = (const float*)d_in[2];
  const void*  rmask = d_in[3];
  const void*  smask = d_in[4];

  char* ws = (char*)d_ws;
  size_t off = 0;
  int* hdr = (int*)(ws + off);            off += 256;
  int* hist = (int*)(ws + off);           off += (size_t)NBIN1*4;
  float* cand_vals = (float*)(ws + off);  off += (size_t)CAND_CAP*4;
  int* cand_idx = (int*)(ws + off);       off += (size_t)CAND_CAP*4;
  float* eq_vals = (float*)(ws + off);    off += (size_t)EQCAP*4;
  int* eq_idx = (int*)(ws + off);         off += (size_t)EQCAP*4;
  float* Hsr = (float*)(ws + off);        off += (size_t)BB*15*4;
  int* pcount = (int*)(ws + off);         off += (size_t)BB*4;
  float* localT = (float*)(ws + off);     off += (size_t)BB*12*4;
  float* sel_vals = (float*)(ws + off);   off += (size_t)LIMIT*4;
  int* sel_idx = (int*)(ws + off);        off += (size_t)LIMIT*4;
  float* sel_ref = (float*)(ws + off);    off += (size_t)LIMIT*3*4;
  float* sel_src = (float*)(ws + off);    off += (size_t)LIMIT*3*4;
  int* counts = (int*)(ws + off);         off += (size_t)BB*4;

  hipMemsetAsync(ws, 0, 256 + (size_t)NBIN1*4, stream);
  hipLaunchKernelGGL(kmode_kernel, dim3(1), dim3(64), 0, stream, rmask, hdr);
  hipLaunchKernelGGL(k1_kernel, dim3(BB), dim3(NN), 0, stream,
                     score, refp, srcp, rmask, smask, hdr, cand_vals, cand_idx, Hsr, pcount);
  hipLaunchKernelGGL(k2_kernel, dim3(2), dim3(256), 0, stream, Hsr, localT);
  hipLaunchKernelGGL(k3a_kernel, dim3(32), dim3(256), 0, stream, hdr, cand_vals, hist);
  hipLaunchKernelGGL(k3b_kernel, dim3(1), dim3(256), 0, stream, hdr, hist);
  hipLaunchKernelGGL(k3c_kernel, dim3(64), dim3(256), 0, stream,
                     hdr, cand_vals, cand_idx, sel_vals, sel_idx, eq_vals, eq_idx);
  hipLaunchKernelGGL(k3d_kernel, dim3(1), dim3(1024), 0, stream,
                     hdr, eq_vals, eq_idx, sel_vals, sel_idx);
  hipLaunchKernelGGL(k3e_kernel, dim3(8), dim3(256), 0, stream,
                     sel_idx, refp, srcp, sel_ref, sel_src);
  hipLaunchKernelGGL(k4_kernel, dim3(BB), dim3(256), 0, stream,
                     localT, sel_vals, sel_ref, sel_src, pcount, counts);
  hipLaunchKernelGGL(k5_kernel, dim3(1), dim3(1024), 0, stream,
                     counts, localT, sel_vals, sel_ref, sel_src, (float*)d_out);
}

// Round 3
// 293.617 us; speedup vs baseline: 4.5053x; 1.0838x over previous
//
#include <hip/hip_runtime.h>
#include <math.h>

#define BB 512
#define NN 128
#define CAND_CAP (512*384)
#define LIMIT 2048
#define EQCAP 16384
#define NBIN1 4096

// ---------------- mask decode (int32 / byte / float32 robustness) -------------
__device__ inline bool read_mask(const void* p, int i, int mode){
  if (mode == 0) return ((const int*)p)[i] != 0;
  if (mode == 1) return ((const unsigned char*)p)[i] != 0;
  return ((const float*)p)[i] != 0.0f;
}

// ---------------- fp32 Kabsch rotation from 3x3 covariance --------------------
__device__ void kabsch_rot_f(const float H[3][3], float R[3][3]){
  float S[3][3];
  for (int i = 0; i < 3; i++)
    for (int j = 0; j < 3; j++){
      float a = 0.f;
      for (int k = 0; k < 3; k++) a += H[k][i]*H[k][j];
      S[i][j] = a;
    }
  float V[3][3] = {{1,0,0},{0,1,0},{0,0,1}};
  for (int sweep = 0; sweep < 12; sweep++){
    float off  = S[0][1]*S[0][1] + S[0][2]*S[0][2] + S[1][2]*S[1][2];
    float base = S[0][0]*S[0][0] + S[1][1]*S[1][1] + S[2][2]*S[2][2];
    if (off <= base*1e-14f + 1e-36f) break;
    for (int p = 0; p < 2; p++)
      for (int q = p+1; q < 3; q++){
        float apq = S[p][q];
        if (fabsf(apq) <= 1e-30f) continue;
        float tau = (S[q][q] - S[p][p]) / (2.f*apq);
        float tt  = (tau >= 0.f ? 1.f : -1.f) / (fabsf(tau) + sqrtf(1.f + tau*tau));
        float c = 1.f / sqrtf(1.f + tt*tt), s = tt*c;
        for (int k = 0; k < 3; k++){ float a=S[k][p], b2=S[k][q]; S[k][p]=c*a-s*b2; S[k][q]=s*a+c*b2; }
        for (int k = 0; k < 3; k++){ float a=S[p][k], b2=S[q][k]; S[p][k]=c*a-s*b2; S[q][k]=s*a+c*b2; }
        for (int k = 0; k < 3; k++){ float a=V[k][p], b2=V[k][q]; V[k][p]=c*a-s*b2; V[k][q]=s*a+c*b2; }
      }
  }
  float lam[3] = { S[0][0], S[1][1], S[2][2] };
  int o0=0,o1=1,o2=2;
  if (lam[o0] < lam[o1]){ int x=o0;o0=o1;o1=x; }
  if (lam[o0] < lam[o2]){ int x=o0;o0=o2;o2=x; }
  if (lam[o1] < lam[o2]){ int x=o1;o1=o2;o2=x; }
  float v0[3]={V[0][o0],V[1][o0],V[2][o0]};
  float v1[3]={V[0][o1],V[1][o1],V[2][o1]};
  float v2[3]={V[0][o2],V[1][o2],V[2][o2]};
  float sig0 = sqrtf(fmaxf(lam[o0], 0.f));
  if (!(sig0 > 1e-12f)){
    for (int i = 0; i < 3; i++) for (int j = 0; j < 3; j++) R[i][j] = (i==j) ? 1.f : 0.f;
    return;
  }
  float u0[3],u1[3],u2[3];
  for (int i = 0; i < 3; i++) u0[i] = H[i][0]*v0[0] + H[i][1]*v0[1] + H[i][2]*v0[2];
  float n0 = sqrtf(u0[0]*u0[0]+u0[1]*u0[1]+u0[2]*u0[2]);
  float in0 = 1.f/n0;
  for (int i = 0; i < 3; i++) u0[i] *= in0;
  for (int i = 0; i < 3; i++) u1[i] = H[i][0]*v1[0] + H[i][1]*v1[1] + H[i][2]*v1[2];
  float dp = u1[0]*u0[0]+u1[1]*u0[1]+u1[2]*u0[2];
  for (int i = 0; i < 3; i++) u1[i] -= dp*u0[i];
  float n1 = sqrtf(u1[0]*u1[0]+u1[1]*u1[1]+u1[2]*u1[2]);
  if (n1 > sig0*1e-5f){
    float in1 = 1.f/n1;
    for (int i = 0; i < 3; i++) u1[i] *= in1;
  } else {
    int k = (fabsf(u0[0])<=fabsf(u0[1]) && fabsf(u0[0])<=fabsf(u0[2])) ? 0 : ((fabsf(u0[1])<=fabsf(u0[2])) ? 1 : 2);
    float e[3] = {0,0,0}; e[k] = 1.f;
    float d2 = e[0]*u0[0]+e[1]*u0[1]+e[2]*u0[2];
    for (int i = 0; i < 3; i++) u1[i] = e[i] - d2*u0[i];
    float nn = 1.f/sqrtf(u1[0]*u1[0]+u1[1]*u1[1]+u1[2]*u1[2]);
    for (int i = 0; i < 3; i++) u1[i] *= nn;
  }
  u2[0] = u0[1]*u1[2] - u0[2]*u1[1];
  u2[1] = u0[2]*u1[0] - u0[0]*u1[2];
  u2[2] = u0[0]*u1[1] - u0[1]*u1[0];
  float cx = v1[1]*v2[2] - v1[2]*v2[1];
  float cy = v1[2]*v2[0] - v1[0]*v2[2];
  float cz = v1[0]*v2[1] - v1[1]*v2[0];
  float detV = v0[0]*cx + v0[1]*cy + v0[2]*cz;  // det(U)=+1 by construction
  float dd = (detV >= 0.f) ? 1.f : -1.f;
  for (int i = 0; i < 3; i++)
    for (int j = 0; j < 3; j++)
      R[i][j] = v0[i]*u0[j] + v1[i]*u1[j] + dd*v2[i]*u2[j];
}

// ---------------- K1: exp, mutual top-3, candidates, per-batch H/sc/rc --------
__global__ __launch_bounds__(128) void k1_kernel(
    const float* __restrict__ score, const float* __restrict__ refp,
    const float* __restrict__ srcp, const void* __restrict__ rmaskp,
    const void* __restrict__ smaskp, int* hdr, float* cand_vals, int* cand_idx,
    float* Hsr, int* pcount)
{
  __shared__ float tile[NN*NN];      // 64 KB exp-score tile
  __shared__ float t3col[NN];
  __shared__ float smaskv[NN];
  __shared__ float srcsh[NN*3];
  __shared__ float red[2][17];
  __shared__ int wsum[2];
  __shared__ int basesh;
  __shared__ int smode;
  const int b = blockIdx.x, t = threadIdx.x;

  // mode detect (wave 0): int32 0/1, byte, or float 0/1.0
  if (t < 64){
    unsigned v = ((const unsigned*)rmaskp)[t];
    bool n01 = !(v == 0u || v == 1u);
    bool nf  = !(v == 0u || v == 0x3F800000u);
    unsigned long long b01 = __ballot(n01), bf = __ballot(nf);
    if (t == 0) smode = (b01 == 0ull) ? 0 : ((bf == 0ull) ? 2 : 1);
  }

  // coalesced load + exp
  const float4* s4 = (const float4*)(score + (size_t)b*NN*NN);
  float4* t4 = (float4*)tile;
  for (int j = t; j < NN*NN/4; j += NN){
    float4 v = s4[j];
    v.x = expf(v.x); v.y = expf(v.y); v.z = expf(v.z); v.w = expf(v.w);
    t4[j] = v;
  }
  __syncthreads();
  const int mode = smode;
  smaskv[t] = read_mask(smaskp, b*NN + t, mode) ? 1.f : 0.f;
  const float rm = read_mask(rmaskp, b*NN + t, mode) ? 1.f : 0.f;
  const float rx = refp[(b*NN+t)*3+0], ry = refp[(b*NN+t)*3+1], rz = refp[(b*NN+t)*3+2];
  srcsh[t*3+0] = srcp[(b*NN+t)*3+0];
  srcsh[t*3+1] = srcp[(b*NN+t)*3+1];
  srcsh[t*3+2] = srcp[(b*NN+t)*3+2];

  // column top-3 (thread t owns column t): 2-way bank alias = free
  float c1=-1e30f, c2=-1e30f, c3=-1e30f;
  for (int n = 0; n < NN; n++){
    float v = tile[n*NN + t];
    if (v > c1){ c3=c2; c2=c1; c1=v; } else if (v > c2){ c3=c2; c2=v; } else if (v > c3){ c3=v; }
  }
  t3col[t] = c3;
  // row top-3 (thread t owns row t), rotated to avoid 64-way conflicts
  float r1=-1e30f, r2=-1e30f, r3v=-1e30f;
  for (int i = 0; i < NN; i++){
    int m = (t + i) & (NN - 1);
    float v = tile[t*NN + m];
    if (v > r1){ r3v=r2; r2=r1; r1=v; } else if (v > r2){ r3v=r2; r2=v; } else if (v > r3v){ r3v=v; }
  }
  __syncthreads();

  // masked pass: keep mutual-top-3 & >CONF & masks; per-thread <=3 candidates
  float wr = 0.f, p0 = 0.f, p1 = 0.f, p2 = 0.f, cntf = 0.f;
  float kv[3]; int km[3]; int cnt = 0;
  for (int i = 0; i < NN; i++){
    int m = (t + i) & (NN - 1);
    float v = tile[t*NN + m];
    bool keep = (rm > 0.f) && (smaskv[m] > 0.f) && (v > 0.05f) && (v >= r3v) && (v >= t3col[m]);
    if (keep){
      cntf += 1.f; wr += v;
      p0 += v*srcsh[m*3+0]; p1 += v*srcsh[m*3+1]; p2 += v*srcsh[m*3+2];
      if (cnt < 3){ kv[cnt] = v; km[cnt] = m; cnt++; }
    } else {
      tile[t*NN + m] = 0.f;
    }
  }
  // block-wide exclusive scan of cnt -> single atomic per block
  int lane = t & 63, wv = t >> 6;
  int x = cnt;
  for (int off = 1; off < 64; off <<= 1){ int y = __shfl_up(x, off); if (lane >= off) x += y; }
  if (lane == 63) wsum[wv] = x;
  __syncthreads();
  if (t == 0) basesh = atomicAdd(&hdr[0], wsum[0] + wsum[1]);
  __syncthreads();
  int base = basesh + (wv == 1 ? wsum[0] : 0) + (x - cnt);
  for (int j = 0; j < cnt; j++){
    int pos = base + j;
    if (pos < CAND_CAP){ cand_vals[pos] = kv[j]; cand_idx[pos] = (b<<14)|(t<<7)|km[j]; }
  }
  __syncthreads();

  // column sums of masked values
  float wc = 0.f;
  for (int n = 0; n < NN; n++) wc += tile[n*NN + t];
  float sx = srcsh[t*3+0], sy = srcsh[t*3+1], sz = srcsh[t*3+2];

  float q[17];
  q[0]=cntf; q[1]=wr;
  q[2]=wr*rx; q[3]=wr*ry; q[4]=wr*rz;       // rc numerator
  q[5]=wc*sx; q[6]=wc*sy; q[7]=wc*sz;       // sc numerator
  q[8]=p0*rx;  q[9]=p0*ry;  q[10]=p0*rz;    // M^[c][d] = sum p_c * ref_d
  q[11]=p1*rx; q[12]=p1*ry; q[13]=p1*rz;
  q[14]=p2*rx; q[15]=p2*ry; q[16]=p2*rz;
  for (int k = 0; k < 17; k++){
    float v = q[k];
    for (int off = 32; off > 0; off >>= 1) v += __shfl_down(v, off);
    if (lane == 0) red[wv][k] = v;
  }
  __syncthreads();
  if (t == 0){
    float tot[17];
    for (int k = 0; k < 17; k++) tot[k] = red[0][k] + red[1][k];
    float Wm = tot[1];
    float denom = Wm + 1e-5f;
    float s = Wm / denom;
    float rcv[3] = { tot[2]/denom, tot[3]/denom, tot[4]/denom };
    float scv[3] = { tot[5]/denom, tot[6]/denom, tot[7]/denom };
    float* o = &Hsr[b*15];
    for (int c = 0; c < 3; c++)
      for (int d = 0; d < 3; d++)
        o[c*3+d] = tot[8 + c*3 + d]/denom - (2.f - s)*scv[c]*rcv[d];
    o[9]=scv[0]; o[10]=scv[1]; o[11]=scv[2];
    o[12]=rcv[0]; o[13]=rcv[1]; o[14]=rcv[2];
    pcount[b] = (int)(tot[0] + 0.5f);
  }
}

// ---------------- K2: per-batch local transforms (fp32) -----------------------
__global__ __launch_bounds__(64) void k2_kernel(const float* __restrict__ Hsr, float* __restrict__ localT){
  int b = blockIdx.x*blockDim.x + threadIdx.x;
  if (b >= BB) return;
  const float* o = &Hsr[b*15];
  float H[3][3];
  for (int c = 0; c < 3; c++) for (int d = 0; d < 3; d++) H[c][d] = o[c*3+d];
  float sc[3] = { o[9], o[10], o[11] }, rc[3] = { o[12], o[13], o[14] };
  float R[3][3];
  kabsch_rot_f(H, R);
  float* T = &localT[b*12];
  for (int i = 0; i < 3; i++) for (int j = 0; j < 3; j++) T[i*3+j] = R[i][j];
  for (int i = 0; i < 3; i++)
    T[9+i] = rc[i] - (R[i][0]*sc[0] + R[i][1]*sc[1] + R[i][2]*sc[2]);
}

// ---------------- K3a: grid histogram of top-12 key bits ----------------------
__global__ __launch_bounds__(256) void k3a_kernel(
    const int* hdr, const float* __restrict__ cand_vals, int* hist)
{
  __shared__ int lh[NBIN1];
  int t = threadIdx.x;
  int Nc = hdr[0]; if (Nc > CAND_CAP) Nc = CAND_CAP;
  for (int j = t; j < NBIN1; j += 256) lh[j] = 0;
  __syncthreads();
  for (int i = blockIdx.x*256 + t; i < Nc; i += gridDim.x*256)
    atomicAdd(&lh[__float_as_uint(cand_vals[i]) >> 20], 1);
  __syncthreads();
  for (int j = t; j < NBIN1; j += 256)
    if (lh[j]) atomicAdd(&hist[j], lh[j]);
}

// ---------------- K3c: per-block bin-select + partition -----------------------
__global__ __launch_bounds__(256) void k3c_kernel(
    int* hdr, const int* __restrict__ hist,
    const float* __restrict__ cand_vals, const int* __restrict__ cand_idx,
    float* sel_vals, int* sel_idx, float* eq_vals, int* eq_idx)
{
  __shared__ int chunk[256];
  __shared__ int sb[2];
  int t = threadIdx.x;
  int Nc = hdr[0]; if (Nc > CAND_CAP) Nc = CAND_CAP;
  // every block recomputes bin1/need from hist (finalized by k3a dispatch)
  {
    int s = 0;
    for (int j = 0; j < 16; j++) s += hist[t*16 + j];
    chunk[t] = s;
    __syncthreads();
    if (t == 0){
      if (Nc <= LIMIT){ sb[0] = -1; sb[1] = 0; }
      else {
        int cum = 0, c = 255;
        for (; c >= 0; c--){ if (cum + chunk[c] >= LIMIT) break; cum += chunk[c]; }
        int bin1 = 0, need = 0;
        for (int b2 = c*16 + 15; b2 >= c*16; b2--){
          if (cum + hist[b2] >= LIMIT){ bin1 = b2; need = LIMIT - cum; break; }
          cum += hist[b2];
        }
        sb[0] = bin1; sb[1] = need;
      }
      if (blockIdx.x == 0){ hdr[4] = sb[0]; hdr[5] = sb[1]; }
    }
    __syncthreads();
  }
  int bin1 = sb[0];
  for (int i = blockIdx.x*256 + t; i < Nc; i += gridDim.x*256){
    float v = cand_vals[i];
    if (bin1 < 0){
      int p = atomicAdd(&hdr[2], 1);
      if (p < LIMIT){ sel_vals[p] = v; sel_idx[p] = cand_idx[i]; }
      continue;
    }
    int bin = (int)(__float_as_uint(v) >> 20);
    if (bin > bin1){
      int p = atomicAdd(&hdr[2], 1);
      if (p < LIMIT){ sel_vals[p] = v; sel_idx[p] = cand_idx[i]; }
    } else if (bin == bin1){
      int q = atomicAdd(&hdr[1], 1);
      if (q < EQCAP){ eq_vals[q] = v; eq_idx[q] = cand_idx[i]; }
    }
  }
}

// ---------------- K3d: refine within boundary bin + gather points -------------
__global__ __launch_bounds__(1024) void k3d_kernel(
    const int* hdr, const float* __restrict__ eq_vals, const int* __restrict__ eq_idx,
    float* sel_vals, int* sel_idx,
    const float* __restrict__ refp, const float* __restrict__ srcp,
    float* sel_ref, float* sel_src)
{
  __shared__ int hist[2048];
  __shared__ int sh[8];
  __shared__ int eqsh[2048];
  int t = threadIdx.x;
  int bin1 = hdr[4];
  int nAbove = hdr[2]; if (nAbove > LIMIT) nAbove = LIMIT;
  bool done = false;
  if (bin1 < 0){
    for (int i = t; i < LIMIT; i += 1024)
      if (i >= nAbove){ sel_vals[i] = 0.f; sel_idx[i] = 0; }
    done = true;
  }
  int neq = 0, need = 0;
  if (!done){
    neq = hdr[1]; if (neq > EQCAP) neq = EQCAP;
    need = hdr[5];
    if (need >= neq){
      for (int i = t; i < neq; i += 1024){ sel_vals[nAbove+i] = eq_vals[i]; sel_idx[nAbove+i] = eq_idx[i]; }
      for (int i = t; i < LIMIT; i += 1024)
        if (i >= nAbove + neq){ sel_vals[i] = 0.f; sel_idx[i] = 0; }
      done = true;
    }
  }
  if (!done){
    // radix on low-20 bits: pass A bits 19..9 (2048 bins)
    for (int i = t; i < 2048; i += 1024) hist[i] = 0;
    __syncthreads();
    for (int i = t; i < neq; i += 1024)
      atomicAdd(&hist[(__float_as_uint(eq_vals[i]) >> 9) & 0x7FF], 1);
    __syncthreads();
    if (t == 0){
      int cum = 0, bin = 0;
      for (int j = 2047; j >= 0; j--){ if (cum + hist[j] >= need){ bin = j; break; } cum += hist[j]; }
      sh[0] = bin; sh[1] = need - cum;
    }
    __syncthreads();
    int binA = sh[0], need2 = sh[1];
    // pass B bits 8..0 (512 bins)
    for (int i = t; i < 2048; i += 1024) hist[i] = 0;
    __syncthreads();
    for (int i = t; i < neq; i += 1024){
      unsigned k = __float_as_uint(eq_vals[i]);
      if ((int)((k >> 9) & 0x7FF) == binA) atomicAdd(&hist[k & 0x1FF], 1);
    }
    __syncthreads();
    if (t == 0){
      int cum = 0, bin = 0;
      for (int j = 511; j >= 0; j--){ if (cum + hist[j] >= need2){ bin = j; break; } cum += hist[j]; }
      sh[2] = bin; sh[4] = 0; sh[5] = 0;
    }
    __syncthreads();
    unsigned Tlow = (((unsigned)binA) << 9) | (unsigned)sh[2];
    unsigned Tkey = (((unsigned)bin1) << 20) | Tlow;
    for (int i = t; i < neq; i += 1024){
      unsigned k = __float_as_uint(eq_vals[i]);
      unsigned k20 = k & 0xFFFFF;
      if (k20 > Tlow){
        int p = atomicAdd(&sh[4], 1);
        sel_vals[nAbove + p] = eq_vals[i]; sel_idx[nAbove + p] = eq_idx[i];
      } else if (k20 == Tlow){
        int q = atomicAdd(&sh[5], 1);
        if (q < 2048) eqsh[q] = eq_idx[i];
      }
    }
    __syncthreads();
    if (t == 0){
      int na2 = sh[4];
      int ne2 = sh[5]; if (ne2 > 2048) ne2 = 2048;
      int take = need - na2; if (take > ne2) take = ne2; if (take < 0) take = 0;
      if (nAbove + na2 + take > LIMIT) take = LIMIT - nAbove - na2;
      // tie-break: smallest flat index first (matches jax.lax.top_k)
      int* eq2 = eqsh;
      for (int j = 0; j < take; j++){
        int mi = j;
        for (int l = j+1; l < ne2; l++) if (eq2[l] < eq2[mi]) mi = l;
        int tmp = eq2[j]; eq2[j] = eq2[mi]; eq2[mi] = tmp;
        sel_vals[nAbove + na2 + j] = __uint_as_float(Tkey);
        sel_idx[nAbove + na2 + j] = eq2[j];
      }
      for (int j = nAbove + na2 + take; j < LIMIT; j++){ sel_vals[j] = 0.f; sel_idx[j] = 0; }
    }
  }
  __syncthreads();   // sel_idx final & visible block-wide; gather points
  for (int p = t; p < LIMIT; p += 1024){
    int idx = sel_idx[p];
    int b = idx >> 14, r = (idx >> 7) & 127, s = idx & 127;
    for (int c = 0; c < 3; c++){
      sel_ref[p*3+c] = refp[(b*NN+r)*3+c];
      sel_src[p*3+c] = srcp[(b*NN+s)*3+c];
    }
  }
}

// ---------------- K4: inlier counts per batch ---------------------------------
__global__ __launch_bounds__(256) void k4_kernel(
    const float* __restrict__ localT, const float* __restrict__ sel_vals,
    const float* __restrict__ sel_ref, const float* __restrict__ sel_src,
    const int* __restrict__ pcount, int* counts)
{
  __shared__ int ired[4];
  int b = blockIdx.x, t = threadIdx.x;
  const float* T = &localT[b*12];
  float R00=T[0],R01=T[1],R02=T[2],R10=T[3],R11=T[4],R12=T[5],R20=T[6],R21=T[7],R22=T[8];
  float tx=T[9], ty=T[10], tz=T[11];
  int c = 0;
  for (int p = t; p < LIMIT; p += 256){
    float v = sel_vals[p];
    if (!(v > 0.f)) continue;
    float sx=sel_src[p*3], sy=sel_src[p*3+1], sz=sel_src[p*3+2];
    float rx=sel_ref[p*3], ry=sel_ref[p*3+1], rz=sel_ref[p*3+2];
    float ax = R00*sx + R01*sy + R02*sz + tx;
    float ay = R10*sx + R11*sy + R12*sz + ty;
    float az = R20*sx + R21*sy + R22*sz + tz;
    float dx = rx-ax, dy = ry-ay, dz = rz-az;
    if (sqrtf(dx*dx + dy*dy + dz*dz) < 0.1f) c++;
  }
  int lane = t & 63, wv = t >> 6;
  for (int off = 32; off > 0; off >>= 1) c += __shfl_down(c, off);
  if (lane == 0) ired[wv] = c;
  __syncthreads();
  if (t == 0) counts[b] = (pcount[b] >= 3) ? (ired[0]+ired[1]+ired[2]+ired[3]) : -1;
}

// ---------------- K5: argmax best + 5x weighted Procrustes --------------------
__global__ __launch_bounds__(256) void k5_kernel(
    const int* __restrict__ counts, const float* __restrict__ localT,
    const float* __restrict__ sel_vals, const float* __restrict__ sel_ref,
    const float* __restrict__ sel_src, float* out)
{
  __shared__ double dred[4][16];
  __shared__ long long lred[4];
  __shared__ float RT[12];
  __shared__ int sbest;
  int t = threadIdx.x, lane = t & 63, wv = t >> 6;
  long long key = (long long)0x8000000000000000LL;
  for (int b = t; b < BB; b += 256){
    long long kk = ((long long)(counts[b] + 2) << 32) | (long long)(511 - b);
    if (kk > key) key = kk;
  }
  for (int off = 32; off > 0; off >>= 1){ long long o = __shfl_down(key, off); if (o > key) key = o; }
  if (lane == 0) lred[wv] = key;
  __syncthreads();
  if (t == 0){
    long long m = lred[0];
    for (int w = 1; w < 4; w++) if (lred[w] > m) m = lred[w];
    sbest = 511 - (int)(m & 0xFFFFFFFFLL);
  }
  __syncthreads();
  if (t < 12) RT[t] = localT[sbest*12 + t];
  __syncthreads();

  for (int iter = 0; iter < 5; iter++){
    float R00=RT[0],R01=RT[1],R02=RT[2];
    float R10=RT[3],R11=RT[4],R12=RT[5];
    float R20=RT[6],R21=RT[7],R22=RT[8];
    float tx=RT[9], ty=RT[10], tz=RT[11];
    double a[16];
    for (int k = 0; k < 16; k++) a[k] = 0.0;
    for (int p = t; p < LIMIT; p += 256){
      float v = sel_vals[p];
      if (!(v > 0.f)) continue;
      float sx=sel_src[p*3], sy=sel_src[p*3+1], sz=sel_src[p*3+2];
      float rx=sel_ref[p*3], ry=sel_ref[p*3+1], rz=sel_ref[p*3+2];
      float ax = R00*sx + R01*sy + R02*sz + tx;
      float ay = R10*sx + R11*sy + R12*sz + ty;
      float az = R20*sx + R21*sy + R22*sz + tz;
      float dx = rx-ax, dy = ry-ay, dz = rz-az;
      if (sqrtf(dx*dx + dy*dy + dz*dz) < 0.1f){
        double w = (double)v;
        a[0] += w;
        a[1] += w*sx; a[2] += w*sy; a[3] += w*sz;
        a[4] += w*rx; a[5] += w*ry; a[6] += w*rz;
        a[7]  += w*sx*rx; a[8]  += w*sx*ry; a[9]  += w*sx*rz;
        a[10] += w*sy*rx; a[11] += w*sy*ry; a[12] += w*sy*rz;
        a[13] += w*sz*rx; a[14] += w*sz*ry; a[15] += w*sz*rz;
      }
    }
    for (int k = 0; k < 16; k++){
      double v = a[k];
      for (int off = 32; off > 0; off >>= 1) v += __shfl_down(v, off);
      if (lane == 0) dred[wv][k] = v;
    }
    __syncthreads();
    if (t == 0){
      double tot[16];
      for (int k = 0; k < 16; k++) tot[k] = dred[0][k]+dred[1][k]+dred[2][k]+dred[3][k];
      double W = tot[0], denom = W + 1e-5, s = W / denom;
      double scv[3] = { tot[1]/denom, tot[2]/denom, tot[3]/denom };
      double rcv[3] = { tot[4]/denom, tot[5]/denom, tot[6]/denom };
      float H[3][3];
      for (int c = 0; c < 3; c++)
        for (int d = 0; d < 3; d++)
          H[c][d] = (float)(tot[7 + c*3 + d]/denom - (2.0 - s)*scv[c]*rcv[d]);
      float R[3][3];
      kabsch_rot_f(H, R);
      for (int i = 0; i < 3; i++) for (int j = 0; j < 3; j++) RT[i*3+j] = R[i][j];
      for (int i = 0; i < 3; i++)
        RT[9+i] = (float)(rcv[i] - ((double)R[i][0]*scv[0] + (double)R[i][1]*scv[1] + (double)R[i][2]*scv[2]));
    }
    __syncthreads();
  }
  if (t == 0){
    out[0]=RT[0];  out[1]=RT[1];  out[2]=RT[2];  out[3]=RT[9];
    out[4]=RT[3];  out[5]=RT[4];  out[6]=RT[5];  out[7]=RT[10];
    out[8]=RT[6];  out[9]=RT[7];  out[10]=RT[8]; out[11]=RT[11];
    out[12]=0.f; out[13]=0.f; out[14]=0.f; out[15]=1.f;
  }
}

// ---------------- host launcher -----------------------------------------------
extern "C" void kernel_launch(void* const* d_in, const int* in_sizes, int n_in,
                              void* d_out, int out_size, void* d_ws, size_t ws_size,
                              hipStream_t stream){
  const float* score = (const float*)d_in[0];
  const float* refp  = (const float*)d_in[1];
  const float* srcp  = (const float*)d_in[2];
  const void*  rmask = d_in[3];
  const void*  smask = d_in[4];

  char* ws = (char*)d_ws;
  size_t off = 0;
  int* hdr = (int*)(ws + off);            off += 256;
  int* hist = (int*)(ws + off);           off += (size_t)NBIN1*4;
  float* cand_vals = (float*)(ws + off);  off += (size_t)CAND_CAP*4;
  int* cand_idx = (int*)(ws + off);       off += (size_t)CAND_CAP*4;
  float* eq_vals = (float*)(ws + off);    off += (size_t)EQCAP*4;
  int* eq_idx = (int*)(ws + off);         off += (size_t)EQCAP*4;
  float* Hsr = (float*)(ws + off);        off += (size_t)BB*15*4;
  int* pcount = (int*)(ws + off);         off += (size_t)BB*4;
  float* localT = (float*)(ws + off);     off += (size_t)BB*12*4;
  float* sel_vals = (float*)(ws + off);   off += (size_t)LIMIT*4;
  int* sel_idx = (int*)(ws + off);        off += (size_t)LIMIT*4;
  float* sel_ref = (float*)(ws + off);    off += (size_t)LIMIT*3*4;
  float* sel_src = (float*)(ws + off);    off += (size_t)LIMIT*3*4;
  int* counts = (int*)(ws + off);         off += (size_t)BB*4;

  hipMemsetAsync(ws, 0, 256 + (size_t)NBIN1*4, stream);
  hipLaunchKernelGGL(k1_kernel, dim3(BB), dim3(NN), 0, stream,
                     score, refp, srcp, rmask, smask, hdr, cand_vals, cand_idx, Hsr, pcount);
  hipLaunchKernelGGL(k2_kernel, dim3(8), dim3(64), 0, stream, Hsr, localT);
  hipLaunchKernelGGL(k3a_kernel, dim3(32), dim3(256), 0, stream, hdr, cand_vals, hist);
  hipLaunchKernelGGL(k3c_kernel, dim3(32), dim3(256), 0, stream,
                     hdr, hist, cand_vals, cand_idx, sel_vals, sel_idx, eq_vals, eq_idx);
  hipLaunchKernelGGL(k3d_kernel, dim3(1), dim3(1024), 0, stream,
                     hdr, eq_vals, eq_idx, sel_vals, sel_idx, refp, srcp, sel_ref, sel_src);
  hipLaunchKernelGGL(k4_kernel, dim3(BB), dim3(256), 0, stream,
                     localT, sel_vals, sel_ref, sel_src, pcount, counts);
  hipLaunchKernelGGL(k5_kernel, dim3(1), dim3(256), 0, stream,
                     counts, localT, sel_vals, sel_ref, sel_src, (float*)d_out);
}